// Round 2
// baseline (610.560 us; speedup 1.0000x reference)
//
#include <hip/hip_runtime.h>
#include <stdint.h>

// SVDQW4A4Linear on MI355X.
// R5: main GEMM moved to int4-exact i8 MFMA (mfma_i32_16x16x64_i8, K=64 ==
//     GS) with per-group f32 scale fixup acc += (f32)S_g * as[t][g]*ws[g][o].
//     Keeps R4's verified 4-phase counted-vmcnt skeleton (now vmcnt(4),
//     4 gloads/window, stage-2-ahead into freed regions). Lora (rank 32)
//     is a bf16 MFMA epilogue into the same f32 accumulators.
//     Staging bytes halve (i8), MFMA ceiling ~1.9x bf16.
// Pipeline:
//   k_wdq   : Bq[o][k] = (i8)qweight
//   k_wlora : BL[o][0:32] = bf16(proj_up)
//   k_prep  : pdT[r][k] = bf16(proj_down^T)
//   k_act   : Aq = (i8)q, asT[g][t] = ascale, AL[t][0:32] = bf16(xs@proj_down)
//   k_gemm  : out = sum_g as*ws*(Aq_g @ Bq_g^T) + AL @ BL^T
//             (256x256 tile, BK=64=group, 8 waves, 160KB LDS)

#define T_DIM 8192
#define IN_DIM 4096
#define OUT_DIM 4096
#define RANK 32
#define CHUNK 512
#define NCHUNK 8   // IN_DIM / CHUNK
#define NG 64      // IN_DIM / 64 groups == K-tiles

typedef unsigned short u16;
typedef __attribute__((ext_vector_type(8))) short short8;
typedef __attribute__((ext_vector_type(4))) float f32x4;
typedef __attribute__((ext_vector_type(4))) int i32x4;
typedef __attribute__((address_space(1))) const unsigned int gas_u32;
typedef __attribute__((address_space(3))) unsigned int las_u32;

__device__ __forceinline__ u16 f2bf(float f) {
  unsigned u = __float_as_uint(f);
  u += 0x7FFFu + ((u >> 16) & 1u);   // RNE; inputs finite
  return (u16)(u >> 16);
}

__device__ __forceinline__ f32x4 cvt4(i32x4 v) {
  f32x4 r;
  r[0] = (float)v[0]; r[1] = (float)v[1];
  r[2] = (float)v[2]; r[3] = (float)v[3];
  return r;
}

// ---------------- weight int4 pack: Bq[o][k] = (i8)qw ----------------
__global__ __launch_bounds__(256) void k_wdq(const int* __restrict__ qw,
                                             char* __restrict__ Bq) {
  int id = blockIdx.x * 256 + threadIdx.x;     // 4096*4096/4 ids
  int4 q = *(const int4*)(qw + (size_t)id * 4);
  unsigned p = (unsigned)(q.x & 255) | ((unsigned)(q.y & 255) << 8) |
               ((unsigned)(q.z & 255) << 16) | ((unsigned)(q.w & 255) << 24);
  ((unsigned*)Bq)[id] = p;
}

// ---------------- proj_up -> BL bf16 [OUT][32] ----------------
__global__ __launch_bounds__(256) void k_wlora(const float* __restrict__ pu,
                                               u16* __restrict__ BL) {
  int id = blockIdx.x * 256 + threadIdx.x;     // 4096*32
  BL[id] = f2bf(pu[id]);
}

// ---------------- proj_down transpose (bf16) ----------------
__global__ __launch_bounds__(256) void k_prep(const float* __restrict__ pd,
                                              u16* __restrict__ pdT) {
  int id = blockIdx.x * 256 + threadIdx.x;     // 131072
  int k = id >> 5, r = id & 31;
  pdT[(size_t)r * IN_DIM + k] = f2bf(pd[(size_t)k * RANK + r]);
}

// ---------------- fused activation quant + lora_down ----------------
// Same verified structure as R4; outputs now: Aq i8, asT f32 [64][T],
// AL bf16 [T][32]. Quant math (IEEE div, rintf, clip) unchanged.
__global__ __launch_bounds__(256) void k_act(const float* __restrict__ x,
                                             const float* __restrict__ smooth,
                                             const u16* __restrict__ pdT,
                                             char* __restrict__ Aq,
                                             u16* __restrict__ AL,
                                             float* __restrict__ asT) {
  __shared__ u16 sxs[16 * 512];        // 16 KB
  __shared__ float sacc[4][16][32];    // 8 KB
  int tid = threadIdx.x;
  int wave = tid >> 6, lane = tid & 63;
  int quad = lane >> 4, l16 = lane & 15;
  int t0 = blockIdx.x * 16;
  int row = tid >> 4;                  // staging token row
  int seg = tid & 15;                  // 32-col segment in chunk
  const float* xrow = x + (size_t)(t0 + row) * IN_DIM;
  char* aqrow = Aq + (size_t)(t0 + row) * IN_DIM;

  f32x4 acc0 = {0.f, 0.f, 0.f, 0.f}, acc1 = {0.f, 0.f, 0.f, 0.f};

  for (int it = 0; it < NCHUNK; ++it) {
    int cbase = it * CHUNK;
    int c0 = cbase + seg * 32;
    float xs[32];
#pragma unroll
    for (int j = 0; j < 8; ++j) {
      float4 xv = *(const float4*)(xrow + c0 + j * 4);
      float4 sv = *(const float4*)(smooth + c0 + j * 4);
      xs[j * 4 + 0] = xv.x / sv.x;     // IEEE div: matches reference xs
      xs[j * 4 + 1] = xv.y / sv.y;
      xs[j * 4 + 2] = xv.z / sv.z;
      xs[j * 4 + 3] = xv.w / sv.w;
    }
    float m = 0.f;
#pragma unroll
    for (int j = 0; j < 32; ++j) m = fmaxf(m, fabsf(xs[j]));
    m = fmaxf(m, __shfl_xor(m, 1));    // pair covers the 64-col group
    float ascale = m / 7.0f;           // IEEE div: matches reference
    if (ascale == 0.0f) ascale = 1.0f;
    if ((seg & 1) == 0)
      asT[(size_t)(c0 >> 6) * T_DIM + (t0 + row)] = ascale;

    __syncthreads();                   // prev chunk's MFMA readers done
#pragma unroll
    for (int j = 0; j < 4; ++j) {      // 4 chunks of 8 values
      short8 s8;
      unsigned lo = 0, hi = 0;
#pragma unroll
      for (int e = 0; e < 8; ++e) {
        float a = xs[j * 8 + e];
        float qf = fminf(7.0f, fmaxf(-8.0f, rintf(a / ascale)));  // half-even
        int qi = (int)qf;
        unsigned ub = (unsigned)(qi & 255);
        if (e < 4) lo |= ub << (8 * e); else hi |= ub << (8 * (e - 4));
        s8[e] = (short)f2bf(a);
      }
      *(uint2*)(aqrow + c0 + j * 8) = make_uint2(lo, hi);    // 8 x i8
      int c = seg * 4 + j;
      int slot = c ^ (row & 7);
      *(short8*)((char*)sxs + (row * 64 + slot) * 16) = s8;  // xs -> LDS
    }
    __syncthreads();
#pragma unroll
    for (int kk = 0; kk < 4; ++kk) {
      int crel = wave * 16 + kk * 4 + quad;    // 8-col chunk index in chunk
      int slot = crel ^ (l16 & 7);
      short8 af = *(const short8*)((const char*)sxs + (l16 * 64 + slot) * 16);
      int kg = cbase + wave * 128 + kk * 32 + quad * 8;
      short8 b0 = *(const short8*)(pdT + (size_t)l16 * IN_DIM + kg);
      short8 b1 = *(const short8*)(pdT + (size_t)(16 + l16) * IN_DIM + kg);
      acc0 = __builtin_amdgcn_mfma_f32_16x16x32_bf16(af, b0, acc0, 0, 0, 0);
      acc1 = __builtin_amdgcn_mfma_f32_16x16x32_bf16(af, b1, acc1, 0, 0, 0);
    }
  }
#pragma unroll
  for (int e = 0; e < 4; ++e) {
    sacc[wave][quad * 4 + e][l16] = acc0[e];
    sacc[wave][quad * 4 + e][16 + l16] = acc1[e];
  }
  __syncthreads();
  for (int t = tid; t < 512; t += 256) {
    int r2 = t >> 5, rk = t & 31;
    float s = sacc[0][r2][rk] + sacc[1][r2][rk] + sacc[2][r2][rk] + sacc[3][r2][rk];
    AL[(size_t)(t0 + r2) * RANK + rk] = f2bf(s);
  }
}

// ---------------- main GEMM ----------------
// 256x256 tile, 512 threads (8 waves, 2M x 4N interleaved-16), 160KB LDS:
//   [0..16K)   Aq buf0   [16K..32K) Bq buf0
//   [32K..48K) Aq buf1   [48K..64K) Bq buf1
//   [64K..128K) as f32 [64][256]    [128K..160K) ws bf16 [64][256]
// i8 tiles [256 rows][64B], 4 slots of 16B, slot = chunk ^ ((r^(r>>2))&3)
// (uniform 2-way bank alias on b128 reads = free; staged via pre-swizzled
// global source + linear LDS dest). Per group t: 4 phases (quadrants),
// 8 i8 MFMA + f32 fixup each; stage tile t+2 into just-freed regions of the
// buffer being read (P2:A.h0, P3:B.h0, P4:A.h1+B.h1); s_waitcnt vmcnt(4)
// once per window — never drained in the main loop. Lora bf16 epilogue
// reuses buf0 region, accumulating into the same f32 acc.
#define MFMAI8 __builtin_amdgcn_mfma_i32_16x16x64_i8
#define MFMABF __builtin_amdgcn_mfma_f32_16x16x32_bf16
#define BAR __builtin_amdgcn_s_barrier

#define STAGEQ(gbase, sbase, h, kt)                                           \
  do {                                                                        \
    const char* _s = (const char*)(gbase) +                                   \
        (size_t)((h)*128 + stq_r) * IN_DIM + (size_t)(kt)*64 + stq_cs * 16;   \
    char* _d = (char*)(sbase) + (h)*8192 + tid * 16;                          \
    __builtin_amdgcn_global_load_lds((gas_u32*)(const void*)_s,               \
                                     (las_u32*)(void*)_d, 16, 0, 0);          \
  } while (0)

#define STAGEL(gbase, sbase, h)                                               \
  do {                                                                        \
    const char* _s = (const char*)(gbase) +                                   \
        (size_t)((h)*128 + stq_r) * 64 + stq_cs * 16;                         \
    char* _d = (char*)(sbase) + (h)*8192 + tid * 16;                          \
    __builtin_amdgcn_global_load_lds((gas_u32*)(const void*)_s,               \
                                     (las_u32*)(void*)_d, 16, 0, 0);          \
  } while (0)

#define LDAQ(base, i) \
  (*(const i32x4*)((const char*)(base) + ((i)*32 + wr16 + l16) * 64 + ((quad ^ swa) << 4)))
#define LDBQ(base, j) \
  (*(const i32x4*)((const char*)(base) + ((j)*64 + wc16 + l16) * 64 + ((quad ^ swb) << 4)))
#define LDAL(base, i) \
  (*(const short8*)((const char*)(base) + ((i)*32 + wr16 + l16) * 64 + ((quad ^ swa) << 4)))
#define LDBL(base, j) \
  (*(const short8*)((const char*)(base) + ((j)*64 + wc16 + l16) * 64 + ((quad ^ swb) << 4)))
#define WSLD(g, j) \
  __uint_as_float((unsigned)sWSp[(g)*256 + (j)*64 + wc16 + l16] << 16)

__global__ __launch_bounds__(512, 2) void k_gemm(const char* __restrict__ Aq,
                                                 const char* __restrict__ Bq,
                                                 const u16* __restrict__ AL,
                                                 const u16* __restrict__ BL,
                                                 const float* __restrict__ asT,
                                                 const float* __restrict__ wsc,
                                                 float* __restrict__ C) {
  extern __shared__ __align__(16) char lds[];   // 163840 B
  const int tid = threadIdx.x;
  const int wave = tid >> 6, lane = tid & 63;
  const int quad = lane >> 4, l16 = lane & 15;
  const int wr16 = (wave >> 2) << 4;           // M offset within 32-row group
  const int wc16 = (wave & 3) << 4;            // N offset within 64-row group
  const int swa = ((wr16 + l16) ^ ((wr16 + l16) >> 2)) & 3;
  const int swb = ((wc16 + l16) ^ ((wc16 + l16) >> 2)) & 3;
  // XCD-aware bijective swizzle (nwg=512, 512%8==0)
  const int swz = (blockIdx.x & 7) * 64 + (blockIdx.x >> 3);
  const int t0 = (swz >> 4) * 256;             // 32 M-tiles
  const int o0 = (swz & 15) * 256;             // 16 N-tiles
  const char* gAq = Aq + (size_t)t0 * IN_DIM;
  const char* gBq = Bq + (size_t)o0 * IN_DIM;
  const char* gAL = (const char*)AL + (size_t)t0 * 64;   // rows of 32 bf16
  const char* gBL = (const char*)BL + (size_t)o0 * 64;
  // staging constants: row-in-half, dest slot, pre-swizzled source chunk
  const int stq_r = tid >> 2;
  const int stq_cs = (tid & 3) ^ ((stq_r ^ (stq_r >> 2)) & 3);

  float* const sASf = (float*)(lds + 65536);
  u16* const sWSp = (u16*)(lds + 131072);

  f32x4 acc[8][4];
#pragma unroll
  for (int i = 0; i < 8; ++i)
#pragma unroll
    for (int j = 0; j < 4; ++j)
      acc[i][j] = (f32x4){0.f, 0.f, 0.f, 0.f};
  const i32x4 zeroi = {0, 0, 0, 0};

  // ---- scale staging (one-time) ----
  for (int v = tid; v < 16384; v += 512) {
    int g = v >> 8, c = v & 255;
    sWSp[v] = f2bf(wsc[(size_t)g * OUT_DIM + o0 + c]);
    sASf[v] = asT[(size_t)g * T_DIM + t0 + c];
  }

  // ---- prologue: tiles 0 and 1 (8 gloads); wait tile0 (leave 4 in flight)
  STAGEQ(gAq, lds, 0, 0);           STAGEQ(gAq, lds, 1, 0);
  STAGEQ(gBq, lds + 16384, 0, 0);   STAGEQ(gBq, lds + 16384, 1, 0);
  STAGEQ(gAq, lds + 32768, 0, 1);   STAGEQ(gAq, lds + 32768, 1, 1);
  STAGEQ(gBq, lds + 49152, 0, 1);   STAGEQ(gBq, lds + 49152, 1, 1);
  asm volatile("s_waitcnt vmcnt(4) lgkmcnt(0)" ::: "memory");
  BAR();

  for (int t = 0; t < NG; ++t) {
    const int cur = t & 1;
    int ts2 = t + 2; if (ts2 > NG - 1) ts2 = NG - 1;   // clamped phantoms
    char* const sAc = cur ? lds + 32768 : lds;
    char* const sBc = cur ? lds + 49152 : lds + 16384;
    const float* asg = sASf + (size_t)t * 256;

    i32x4 a[4], b0v[2], b1v[2];
    f32x4 as_lo[4], as_hi[4];

    // ---- P1: m0 x n0 (reads Aq.h0, Bq.h0) ----
#pragma unroll
    for (int i = 0; i < 4; ++i) {
      a[i] = LDAQ(sAc, i);
      as_lo[i] = *(const f32x4*)(asg + i * 32 + wr16 + quad * 4);
    }
    b0v[0] = LDBQ(sBc, 0); b0v[1] = LDBQ(sBc, 1);
    float w0 = WSLD(t, 0), w1 = WSLD(t, 1);
    BAR();
    __builtin_amdgcn_s_setprio(1);
#pragma unroll
    for (int i = 0; i < 4; ++i)
#pragma unroll
      for (int j = 0; j < 2; ++j) {
        i32x4 q4 = MFMAI8(a[i], b0v[j], zeroi, 0, 0, 0);
        acc[i][j] += cvt4(q4) * (as_lo[i] * (j ? w1 : w0));
      }
    __builtin_amdgcn_s_setprio(0);
    BAR();

    // ---- P2: m0 x n1 (reads Bq.h1; A regs reused) ----
    b1v[0] = LDBQ(sBc, 2); b1v[1] = LDBQ(sBc, 3);
    float w2 = WSLD(t, 2), w3 = WSLD(t, 3);
    STAGEQ(gAq, sAc, 0, ts2);            // Aq.h0(t+2): freed by P1
    BAR();
    __builtin_amdgcn_s_setprio(1);
#pragma unroll
    for (int i = 0; i < 4; ++i)
#pragma unroll
      for (int j = 0; j < 2; ++j) {
        i32x4 q4 = MFMAI8(a[i], b1v[j], zeroi, 0, 0, 0);
        acc[i][2 + j] += cvt4(q4) * (as_lo[i] * (j ? w3 : w2));
      }
    __builtin_amdgcn_s_setprio(0);
    BAR();

    // ---- P3: m1 x n0 (reads Aq.h1; B n0 regs reused) ----
#pragma unroll
    for (int i = 0; i < 4; ++i) {
      a[i] = LDAQ(sAc, 4 + i);
      as_hi[i] = *(const f32x4*)(asg + (4 + i) * 32 + wr16 + quad * 4);
    }
    STAGEQ(gBq, sBc, 0, ts2);            // Bq.h0(t+2): freed by P1
    BAR();
    __builtin_amdgcn_s_setprio(1);
#pragma unroll
    for (int i = 0; i < 4; ++i)
#pragma unroll
      for (int j = 0; j < 2; ++j) {
        i32x4 q4 = MFMAI8(a[i], b0v[j], zeroi, 0, 0, 0);
        acc[4 + i][j] += cvt4(q4) * (as_hi[i] * (j ? w1 : w0));
      }
    __builtin_amdgcn_s_setprio(0);
    BAR();

    // ---- P4: m1 x n1 (no LDS tile reads) ----
    STAGEQ(gAq, sAc, 1, ts2);            // Aq.h1(t+2): freed by P3
    STAGEQ(gBq, sBc, 1, ts2);            // Bq.h1(t+2): freed by P2
    BAR();
    __builtin_amdgcn_s_setprio(1);
#pragma unroll
    for (int i = 0; i < 4; ++i)
#pragma unroll
      for (int j = 0; j < 2; ++j) {
        i32x4 q4 = MFMAI8(a[i], b1v[j], zeroi, 0, 0, 0);
        acc[4 + i][2 + j] += cvt4(q4) * (as_hi[i] * (j ? w3 : w2));
      }
    __builtin_amdgcn_s_setprio(0);
    // tile t+1 fully landed; only the 4 t+2 stages remain in flight
    asm volatile("s_waitcnt vmcnt(4)" ::: "memory");
    BAR();
  }

  // ---- lora epilogue: rank-32 bf16 MFMA into the same accumulators ----
  asm volatile("s_waitcnt vmcnt(0)" ::: "memory");   // drain phantoms
  BAR();
  STAGEL(gAL, lds, 0);          STAGEL(gAL, lds, 1);
  STAGEL(gBL, lds + 16384, 0);  STAGEL(gBL, lds + 16384, 1);
  asm volatile("s_waitcnt vmcnt(0)" ::: "memory");
  BAR();
#pragma unroll
  for (int i = 0; i < 8; ++i) {
    short8 al = LDAL(lds, i);
#pragma unroll
    for (int j = 0; j < 4; ++j)
      acc[i][j] = MFMABF(al, LDBL(lds + 16384, j), acc[i][j], 0, 0, 0);
  }

  // ---- C store (same mapping as R4) ----
#pragma unroll
  for (int i = 0; i < 8; ++i) {
    const int row = t0 + i * 32 + wr16 + quad * 4;
#pragma unroll
    for (int j = 0; j < 4; ++j) {
      const int col = o0 + j * 64 + wc16 + l16;
#pragma unroll
      for (int e = 0; e < 4; ++e)
        C[(size_t)(row + e) * OUT_DIM + col] = acc[i][j][e];
    }
  }
}

extern "C" void kernel_launch(void* const* d_in, const int* in_sizes, int n_in,
                              void* d_out, int out_size, void* d_ws, size_t ws_size,
                              hipStream_t stream) {
  const float* x      = (const float*)d_in[0];
  const int*   qw     = (const int*)d_in[1];
  const float* wsc    = (const float*)d_in[2];
  const float* smooth = (const float*)d_in[3];
  const float* pd     = (const float*)d_in[4];
  const float* pu     = (const float*)d_in[5];
  float* out = (float*)d_out;

  char* ws = (char*)d_ws;
  char*  Aq  = ws;                                   // 33,554,432 B
  char*  Bq  = ws + 33554432;                        // 16,777,216 B
  u16*   AL  = (u16*)(ws + 50331648);                //    524,288 B
  u16*   BL  = (u16*)(ws + 50855936);                //    262,144 B
  float* asT = (float*)(ws + 51118080);              //  2,097,152 B
  u16*   pdT = (u16*)(ws + 53215232);                //    262,144 B

  static int attr_set = 0;
  if (!attr_set) {
    hipFuncSetAttribute(reinterpret_cast<const void*>(k_gemm),
                        hipFuncAttributeMaxDynamicSharedMemorySize, 163840);
    attr_set = 1;
  }

  k_wdq  <<<dim3(16384), dim3(256), 0, stream>>>(qw, Bq);
  k_wlora<<<dim3(512), dim3(256), 0, stream>>>(pu, BL);
  k_prep <<<dim3(IN_DIM * RANK / 256), dim3(256), 0, stream>>>(pd, pdT);
  k_act  <<<dim3(T_DIM / 16), dim3(256), 0, stream>>>(x, smooth, pdT, Aq, AL, asT);
  k_gemm <<<dim3(512), dim3(512), 163840, stream>>>(Aq, Bq, AL, BL, asT, wsc, out);
}

// Round 3
// 554.270 us; speedup vs baseline: 1.1016x; 1.1016x over previous
//
#include <hip/hip_runtime.h>
#include <stdint.h>

// SVDQW4A4Linear on MI355X.
// R6: R5's i8+fixup regressed (fixup VALU ~2.6x the MFMA time, MfmaUtil 17%).
//     Full revert to R4's verified bf16 pipeline; k_gemm keeps R4's exact
//     4-phase counted-vmcnt sync skeleton but switches micro-tiles to
//     mfma_f32_32x32x16_bf16 (+15% MFMA rate, half the MFMA instruction
//     count, identical LDS traffic and region lifetimes).
// Pipeline:
//   k_wdq   : B'[o][0:4096]    = bf16(qweight * wscale)
//   k_wlora : B'[o][4096:4160] = bf16(proj_up) | zeros
//   k_prep  : pdT[r][k] = bf16(proj_down^T)
//   k_act   : A'[t][0:4096] = bf16(xdq), A'[t][4096:4128] = bf16(xs@proj_down),
//             A'[t][4128:4160] = 0
//   k_gemm  : out = A' @ B'^T (256x256 tile, BK=64, 8 waves, 32x32x16 MFMA)

#define T_DIM 8192
#define IN_DIM 4096
#define OUT_DIM 4096
#define RANK 32
#define KP 4160
#define LORA_OFF 4096
#define ZPAD_OFF 4128
#define CHUNK 512
#define NCHUNK 8   // IN_DIM / CHUNK
#define NT 65      // KP / 64 K-tiles

typedef unsigned short u16;
typedef __attribute__((ext_vector_type(8))) short short8;
typedef __attribute__((ext_vector_type(4))) float f32x4;
typedef __attribute__((ext_vector_type(16))) float f32x16;
typedef __attribute__((address_space(1))) const unsigned int gas_u32;
typedef __attribute__((address_space(3))) unsigned int las_u32;

__device__ __forceinline__ u16 f2bf(float f) {
  unsigned u = __float_as_uint(f);
  u += 0x7FFFu + ((u >> 16) & 1u);   // RNE; inputs finite
  return (u16)(u >> 16);
}

// ---------------- weight dequant into B' ----------------
__global__ __launch_bounds__(256) void k_wdq(const int* __restrict__ qw,
                                             const float* __restrict__ wsc,
                                             u16* __restrict__ B) {
  int o = blockIdx.x >> 2;
  int k0 = ((blockIdx.x & 3) * 256 + threadIdx.x) * 4;
  int4 q = *(const int4*)(qw + (size_t)o * IN_DIM + k0);
  float s = wsc[(k0 >> 6) * OUT_DIM + o];
  ushort4 r;
  r.x = f2bf((float)q.x * s);
  r.y = f2bf((float)q.y * s);
  r.z = f2bf((float)q.z * s);
  r.w = f2bf((float)q.w * s);
  *(ushort4*)(B + (size_t)o * KP + k0) = r;
}

// ---------------- proj_up + zero pad into B' ----------------
__global__ __launch_bounds__(256) void k_wlora(const float* __restrict__ pu,
                                               u16* __restrict__ B) {
  int id = blockIdx.x * 256 + threadIdx.x;   // 4096*64
  int o = id >> 6, c = id & 63;
  u16 v = 0;
  if (c < RANK) v = f2bf(pu[o * RANK + c]);
  B[(size_t)o * KP + LORA_OFF + c] = v;
}

// ---------------- proj_down transpose (bf16) ----------------
__global__ __launch_bounds__(256) void k_prep(const float* __restrict__ pd,
                                              u16* __restrict__ pdT) {
  int id = blockIdx.x * 256 + threadIdx.x;   // 131072
  int k = id >> 5, r = id & 31;
  pdT[(size_t)r * IN_DIM + k] = f2bf(pd[(size_t)k * RANK + r]);
}

// ---------------- fused activation quant + lora_down ----------------
// R4-exact. Block: 256 threads, 16 tokens, full K=4096 in chunks of 512.
__global__ __launch_bounds__(256) void k_act(const float* __restrict__ x,
                                             const float* __restrict__ smooth,
                                             const u16* __restrict__ pdT,
                                             u16* __restrict__ A) {
  __shared__ u16 sxs[16 * 512];        // 16 KB
  __shared__ float sacc[4][16][32];    // 8 KB
  int tid = threadIdx.x;
  int wave = tid >> 6, lane = tid & 63;
  int quad = lane >> 4, l16 = lane & 15;
  int t0 = blockIdx.x * 16;
  int row = tid >> 4;                  // staging token row
  int seg = tid & 15;                  // 32-col segment in chunk
  const float* xrow = x + (size_t)(t0 + row) * IN_DIM;
  u16* arow = A + (size_t)(t0 + row) * KP;

  f32x4 acc0 = {0.f, 0.f, 0.f, 0.f}, acc1 = {0.f, 0.f, 0.f, 0.f};

  for (int it = 0; it < NCHUNK; ++it) {
    int cbase = it * CHUNK;
    int c0 = cbase + seg * 32;
    float xs[32];
#pragma unroll
    for (int j = 0; j < 8; ++j) {
      float4 xv = *(const float4*)(xrow + c0 + j * 4);
      float4 sv = *(const float4*)(smooth + c0 + j * 4);
      xs[j * 4 + 0] = xv.x / sv.x;     // IEEE div: matches reference xs
      xs[j * 4 + 1] = xv.y / sv.y;
      xs[j * 4 + 2] = xv.z / sv.z;
      xs[j * 4 + 3] = xv.w / sv.w;
    }
    float m = 0.f;
#pragma unroll
    for (int j = 0; j < 32; ++j) m = fmaxf(m, fabsf(xs[j]));
    m = fmaxf(m, __shfl_xor(m, 1));    // pair covers the 64-col group
    float ascale = m / 7.0f;           // IEEE div: matches reference
    if (ascale == 0.0f) ascale = 1.0f;

    __syncthreads();                   // prev chunk's MFMA readers done
#pragma unroll
    for (int j = 0; j < 4; ++j) {      // 4 chunks of 8 bf16
      short8 w8, s8;
#pragma unroll
      for (int e = 0; e < 8; ++e) {
        float a = xs[j * 8 + e];
        float q = fminf(7.0f, fmaxf(-8.0f, rintf(a / ascale)));  // half-even
        w8[e] = (short)f2bf(q * ascale);
        s8[e] = (short)f2bf(a);
      }
      *(short8*)(arow + c0 + j * 8) = w8;                 // xdq -> A'
      int c = seg * 4 + j;
      int slot = c ^ (row & 7);
      *(short8*)((char*)sxs + (row * 64 + slot) * 16) = s8;  // xs -> LDS
    }
    __syncthreads();
#pragma unroll
    for (int kk = 0; kk < 4; ++kk) {
      int crel = wave * 16 + kk * 4 + quad;    // 8-col chunk index in chunk
      int slot = crel ^ (l16 & 7);
      short8 af = *(const short8*)((const char*)sxs + (l16 * 64 + slot) * 16);
      int kg = cbase + wave * 128 + kk * 32 + quad * 8;
      short8 b0 = *(const short8*)(pdT + (size_t)l16 * IN_DIM + kg);
      short8 b1 = *(const short8*)(pdT + (size_t)(16 + l16) * IN_DIM + kg);
      acc0 = __builtin_amdgcn_mfma_f32_16x16x32_bf16(af, b0, acc0, 0, 0, 0);
      acc1 = __builtin_amdgcn_mfma_f32_16x16x32_bf16(af, b1, acc1, 0, 0, 0);
    }
  }
  // split-K reduce across waves; C layout: col=l16 (rank), row=quad*4+e (token)
#pragma unroll
  for (int e = 0; e < 4; ++e) {
    sacc[wave][quad * 4 + e][l16] = acc0[e];
    sacc[wave][quad * 4 + e][16 + l16] = acc1[e];
  }
  __syncthreads();
  for (int t = tid; t < 512; t += 256) {
    int r2 = t >> 5, rk = t & 31;
    float s = sacc[0][r2][rk] + sacc[1][r2][rk] + sacc[2][r2][rk] + sacc[3][r2][rk];
    A[(size_t)(t0 + r2) * KP + LORA_OFF + rk] = f2bf(s);
  }
  // zero pad cols 4128..4159: 16 rows x 32 cols, 2 u16 per thread
  {
    int r2 = tid >> 4, c2 = (tid & 15) * 2;
    *(unsigned*)(A + (size_t)(t0 + r2) * KP + ZPAD_OFF + c2) = 0u;
  }
}

// ---------------- main GEMM: out = A'[T][KP] @ B'[OUT][KP]^T ----------------
// 256x256 tile, BK=64, 512 threads (8 waves, 2M x 4N), 128 KiB dynamic LDS.
// R4's exact sync skeleton (phases, barriers, stages, vmcnt(6)); micro-tile
// switched to mfma_f32_32x32x16_bf16. Per wave: 4 m-tiles x 2 n-tiles of
// 32x32, K=64 as 4 k-steps of 16. m-tiles 0,1 in A-half0 / 2,3 in A-half1;
// n-tile 0 in B-half0 / 1 in B-half1 -> identical region lifetimes to R4:
//   P1 (n0 x m01): reads A-h0 + B-h0 ; stage Am1(t+1)->nxt
//   P2 (n1 x m01): reads B-h1        ; stage A-h0(t+2)->cur (freed by P1)
//   P3 (n0 x m23): reads A-h1        ; stage B-h0(t+2)->cur (freed by P1)
//   P4 (n1 x m23): no reads          ; stage B-h1(t+2)->cur (freed by P2)
//   s_waitcnt vmcnt(6) once per window; never drained in the main loop.
#define MFMA32 __builtin_amdgcn_mfma_f32_32x32x16_bf16
#define BAR __builtin_amdgcn_s_barrier

#define STAGE(gbase, sbase, h, ts)                                            \
  do {                                                                        \
    const u16* _s = (gbase) + (size_t)((h)*128 + stg_r) * KP + (ts)*64 + stg_sc * 8; \
    u16* _d = (sbase) + ((h)*128 + stg_r) * 64 + stg_c * 8;                   \
    __builtin_amdgcn_global_load_lds((gas_u32*)(const void*)_s,               \
                                     (las_u32*)(void*)_d, 16, 0, 0);          \
    __builtin_amdgcn_global_load_lds((gas_u32*)(const void*)(_s + (size_t)8 * KP), \
                                     (las_u32*)(void*)(_d + 8 * 64), 16, 0, 0); \
  } while (0)

// fragment read: row = tile row (0..255), ks = k-step (0..3); lane lhi picks
// the 8-element k-half. slot XOR matches the staging pre-swizzle (c ^ (r&7)).
#define FR(base, row, ks) \
  (*(const short8*)((base) + (row) * 64 + ((((ks)*2 + lhi) ^ ((row) & 7)) * 8)))

__global__ __launch_bounds__(512, 2) void k_gemm(const u16* __restrict__ A,
                                                 const u16* __restrict__ B,
                                                 float* __restrict__ C) {
  extern __shared__ __align__(16) u16 lds[];   // 131072 B
  const int tid = threadIdx.x;
  const int wave = tid >> 6, lane = tid & 63;
  const int l31 = lane & 31, lhi = lane >> 5;
  const int wr = wave >> 2, wc = wave & 3;
  const int arow0 = wr * 32 + l31;             // m-tile 0 row; mt: +(mt&1)*64+(mt>>1)*128
  const int brow0 = wc * 32 + l31;             // n-tile 0 row; nt1: +128
  // XCD-aware bijective swizzle (nwg=512, 512%8==0)
  const int swz = (blockIdx.x & 7) * 64 + (blockIdx.x >> 3);
  const int t0 = (swz >> 4) * 256;             // 32 M-tiles
  const int o0 = (swz & 15) * 256;             // 16 N-tiles
  const u16* gA = A + (size_t)t0 * KP;
  const u16* gB = B + (size_t)o0 * KP;
  // staging constants: row within 128-row half, LDS chunk slot, source chunk
  const int stg_r = wave * 16 + (lane >> 3);
  const int stg_c = lane & 7;
  const int stg_sc = stg_c ^ (lane >> 3);

  u16* const sA0 = lds;
  u16* const sB0 = lds + 16384;
  u16* const sA1 = lds + 32768;
  u16* const sB1 = lds + 32768 + 16384;

  f32x16 acc[4][2];
#pragma unroll
  for (int i = 0; i < 4; ++i)
#pragma unroll
    for (int j = 0; j < 2; ++j)
#pragma unroll
      for (int r = 0; r < 16; ++r)
        acc[i][j][r] = 0.f;

  // Prologue: tile0 complete + 3 halves of tile1; leaves the steady-state
  // in-flight set {Am0(1), Bn0(1), Bn1(1)} == 3 halves == vmcnt(6).
  STAGE(gA, sA0, 0, 0);
  STAGE(gB, sB0, 0, 0);
  STAGE(gB, sB0, 1, 0);
  STAGE(gA, sA0, 1, 0);
  STAGE(gA, sA1, 0, 1);
  STAGE(gB, sB1, 0, 1);
  STAGE(gB, sB1, 1, 1);
  asm volatile("s_waitcnt vmcnt(6)" ::: "memory");
  BAR();

  for (int t = 0; t < NT; ++t) {
    const int cur = t & 1;
    int ts1 = t + 1; if (ts1 >= NT) ts1 = NT - 1;   // clamped phantom stages
    int ts2 = t + 2; if (ts2 >= NT) ts2 = NT - 1;   // keep vmcnt counts uniform
    u16* const sAc = cur ? sA1 : sA0;
    u16* const sBc = cur ? sB1 : sB0;
    u16* const sAn = cur ? sA0 : sA1;

    short8 a[2][4], b0[4], b1[4];

    // ---- P1: n0 x m{0,1} (reads A-h0, B-h0) ----
#pragma unroll
    for (int mt = 0; mt < 2; ++mt)
#pragma unroll
      for (int ks = 0; ks < 4; ++ks)
        a[mt][ks] = FR(sAc, arow0 + mt * 64, ks);
#pragma unroll
    for (int ks = 0; ks < 4; ++ks)
      b0[ks] = FR(sBc, brow0, ks);
    STAGE(gA, sAn, 1, ts1);            // Am1(t+1); region freed at t-1's P3
    BAR();
    __builtin_amdgcn_s_setprio(1);
#pragma unroll
    for (int mt = 0; mt < 2; ++mt)
#pragma unroll
      for (int ks = 0; ks < 4; ++ks)
        acc[mt][0] = MFMA32(a[mt][ks], b0[ks], acc[mt][0], 0, 0, 0);
    __builtin_amdgcn_s_setprio(0);
    BAR();

    // ---- P2: n1 x m{0,1} (reads B-h1; A regs reused) ----
#pragma unroll
    for (int ks = 0; ks < 4; ++ks)
      b1[ks] = FR(sBc, brow0 + 128, ks);
    STAGE(gA, sAc, 0, ts2);            // A-h0(t+2); region freed by P1 reads
    BAR();
    __builtin_amdgcn_s_setprio(1);
#pragma unroll
    for (int mt = 0; mt < 2; ++mt)
#pragma unroll
      for (int ks = 0; ks < 4; ++ks)
        acc[mt][1] = MFMA32(a[mt][ks], b1[ks], acc[mt][1], 0, 0, 0);
    __builtin_amdgcn_s_setprio(0);
    BAR();

    // ---- P3: n0 x m{2,3} (reads A-h1; B n0 regs reused) ----
#pragma unroll
    for (int mt = 0; mt < 2; ++mt)
#pragma unroll
      for (int ks = 0; ks < 4; ++ks)
        a[mt][ks] = FR(sAc, arow0 + 128 + mt * 64, ks);
    STAGE(gB, sBc, 0, ts2);            // B-h0(t+2); region freed by P1 reads
    BAR();
    __builtin_amdgcn_s_setprio(1);
#pragma unroll
    for (int mt = 0; mt < 2; ++mt)
#pragma unroll
      for (int ks = 0; ks < 4; ++ks)
        acc[2 + mt][0] = MFMA32(a[mt][ks], b0[ks], acc[2 + mt][0], 0, 0, 0);
    __builtin_amdgcn_s_setprio(0);
    BAR();

    // ---- P4: n1 x m{2,3} (no LDS reads) ----
    STAGE(gB, sBc, 1, ts2);            // B-h1(t+2); region freed by P2 reads
    BAR();
    __builtin_amdgcn_s_setprio(1);
#pragma unroll
    for (int mt = 0; mt < 2; ++mt)
#pragma unroll
      for (int ks = 0; ks < 4; ++ks)
        acc[2 + mt][1] = MFMA32(a[mt][ks], b1[ks], acc[2 + mt][1], 0, 0, 0);
    __builtin_amdgcn_s_setprio(0);
    // Wait tile t+1 fully landed (= everything except the 3 halves of t+2
    // staged this window). Never drains in-flight prefetch to 0.
    asm volatile("s_waitcnt vmcnt(6)" ::: "memory");
    BAR();
  }

  // Epilogue: 32x32 C/D layout (m74/m101): col = lane&31,
  // row = (reg&3) + 8*(reg>>2) + 4*(lane>>5).
#pragma unroll
  for (int mt = 0; mt < 4; ++mt) {
    const int rb = t0 + (mt >> 1) * 128 + (mt & 1) * 64 + wr * 32 + 4 * lhi;
#pragma unroll
    for (int nt = 0; nt < 2; ++nt) {
      const int cb = o0 + nt * 128 + wc * 32 + l31;
#pragma unroll
      for (int r = 0; r < 16; ++r)
        C[(size_t)(rb + (r & 3) + 8 * (r >> 2)) * OUT_DIM + cb] = acc[mt][nt][r];
    }
  }
}

extern "C" void kernel_launch(void* const* d_in, const int* in_sizes, int n_in,
                              void* d_out, int out_size, void* d_ws, size_t ws_size,
                              hipStream_t stream) {
  const float* x      = (const float*)d_in[0];
  const int*   qw     = (const int*)d_in[1];
  const float* wsc    = (const float*)d_in[2];
  const float* smooth = (const float*)d_in[3];
  const float* pd     = (const float*)d_in[4];
  const float* pu     = (const float*)d_in[5];
  float* out = (float*)d_out;

  char* ws = (char*)d_ws;
  u16* A   = (u16*)ws;                                     // 68,157,440 B
  u16* B   = (u16*)(ws + 68157440);                        // 34,078,720 B
  u16* pdT = (u16*)(ws + 68157440 + 34078720);             // 262,144 B

  static int attr_set = 0;
  if (!attr_set) {
    hipFuncSetAttribute(reinterpret_cast<const void*>(k_gemm),
                        hipFuncAttributeMaxDynamicSharedMemorySize, 131072);
    attr_set = 1;
  }

  k_wdq  <<<dim3(OUT_DIM * 4), dim3(256), 0, stream>>>(qw, wsc, B);
  k_wlora<<<dim3(OUT_DIM * 64 / 256), dim3(256), 0, stream>>>(pu, B);
  k_prep <<<dim3(IN_DIM * RANK / 256), dim3(256), 0, stream>>>(pd, pdT);
  k_act  <<<dim3(T_DIM / 16), dim3(256), 0, stream>>>(x, smooth, pdT, A);
  k_gemm <<<dim3(512), dim3(512), 131072, stream>>>(A, B, out);
}

// Round 4
// 529.520 us; speedup vs baseline: 1.1530x; 1.0467x over previous
//
#include <hip/hip_runtime.h>
#include <stdint.h>

// SVDQW4A4Linear on MI355X.
// R7: k_gemm reverted to R4-exact (R6's 32x32 micro-tile regressed: 25.6M LDS
//     bank conflicts intrinsic to its fragment read shape; R4 measured 0).
//     Experiment: k_act split 4-way over K (slice=1024 cols; per-group amax
//     spans 64 cols so quant math is bit-identical). 512->2048 blocks
//     (2->8 blocks/CU) to hide HBM latency + barrier drains. Rank-32
//     partials go to lpart[4][T][32] f32; new k_fixup sums them -> bf16
//     lora cols + zero pad.
// Pipeline:
//   k_wdq   : B'[o][0:4096]    = bf16(qweight * wscale)
//   k_wlora : B'[o][4096:4160] = bf16(proj_up) | zeros
//   k_prep  : pdT[r][k] = bf16(proj_down^T)
//   k_act   : A'[t][s*1024:(s+1)*1024] = bf16(xdq), lpart[s][t][:] = partial
//   k_fixup : A'[t][4096:4128] = bf16(sum_s lpart), A'[t][4128:4160] = 0
//   k_gemm  : out = A' @ B'^T (256x256 tile, BK=64, 8 waves, 16x16x32 MFMA)

#define T_DIM 8192
#define IN_DIM 4096
#define OUT_DIM 4096
#define RANK 32
#define KP 4160
#define LORA_OFF 4096
#define ZPAD_OFF 4128
#define CHUNK 512
#define NT 65      // KP / 64 K-tiles

typedef unsigned short u16;
typedef __attribute__((ext_vector_type(8))) short short8;
typedef __attribute__((ext_vector_type(4))) float f32x4;
typedef __attribute__((address_space(1))) const unsigned int gas_u32;
typedef __attribute__((address_space(3))) unsigned int las_u32;

__device__ __forceinline__ u16 f2bf(float f) {
  unsigned u = __float_as_uint(f);
  u += 0x7FFFu + ((u >> 16) & 1u);   // RNE; inputs finite
  return (u16)(u >> 16);
}

// ---------------- weight dequant into B' ----------------
__global__ __launch_bounds__(256) void k_wdq(const int* __restrict__ qw,
                                             const float* __restrict__ wsc,
                                             u16* __restrict__ B) {
  int o = blockIdx.x >> 2;
  int k0 = ((blockIdx.x & 3) * 256 + threadIdx.x) * 4;
  int4 q = *(const int4*)(qw + (size_t)o * IN_DIM + k0);
  float s = wsc[(k0 >> 6) * OUT_DIM + o];
  ushort4 r;
  r.x = f2bf((float)q.x * s);
  r.y = f2bf((float)q.y * s);
  r.z = f2bf((float)q.z * s);
  r.w = f2bf((float)q.w * s);
  *(ushort4*)(B + (size_t)o * KP + k0) = r;
}

// ---------------- proj_up + zero pad into B' ----------------
__global__ __launch_bounds__(256) void k_wlora(const float* __restrict__ pu,
                                               u16* __restrict__ B) {
  int id = blockIdx.x * 256 + threadIdx.x;   // 4096*64
  int o = id >> 6, c = id & 63;
  u16 v = 0;
  if (c < RANK) v = f2bf(pu[o * RANK + c]);
  B[(size_t)o * KP + LORA_OFF + c] = v;
}

// ---------------- proj_down transpose (bf16) ----------------
__global__ __launch_bounds__(256) void k_prep(const float* __restrict__ pd,
                                              u16* __restrict__ pdT) {
  int id = blockIdx.x * 256 + threadIdx.x;   // 131072
  int k = id >> 5, r = id & 31;
  pdT[(size_t)r * IN_DIM + k] = f2bf(pd[(size_t)k * RANK + r]);
}

// ---------------- fused activation quant + partial lora_down ----------------
// Grid 2048 = 512 token-tiles x 4 K-slices. Block: 256 threads, 16 tokens,
// K-slice of 1024 cols (2 chunks of 512). Quant math identical to R4.
// Rank-32 partial sums (this slice) -> lpart[slice][t][rk] (f32).
__global__ __launch_bounds__(256) void k_act(const float* __restrict__ x,
                                             const float* __restrict__ smooth,
                                             const u16* __restrict__ pdT,
                                             u16* __restrict__ A,
                                             float* __restrict__ lpart) {
  __shared__ u16 sxs[16 * 512];        // 16 KB
  __shared__ float sacc[4][16][32];    // 8 KB
  int tid = threadIdx.x;
  int wave = tid >> 6, lane = tid & 63;
  int quad = lane >> 4, l16 = lane & 15;
  int tile = blockIdx.x & 511;
  int slice = blockIdx.x >> 9;         // 0..3, covers cols [slice*1024, +1024)
  int t0 = tile * 16;
  int row = tid >> 4;                  // staging token row
  int seg = tid & 15;                  // 32-col segment in chunk
  const float* xrow = x + (size_t)(t0 + row) * IN_DIM;
  u16* arow = A + (size_t)(t0 + row) * KP;

  f32x4 acc0 = {0.f, 0.f, 0.f, 0.f}, acc1 = {0.f, 0.f, 0.f, 0.f};

  for (int it = 0; it < 2; ++it) {
    int cbase = slice * 1024 + it * CHUNK;
    int c0 = cbase + seg * 32;
    float xs[32];
#pragma unroll
    for (int j = 0; j < 8; ++j) {
      float4 xv = *(const float4*)(xrow + c0 + j * 4);
      float4 sv = *(const float4*)(smooth + c0 + j * 4);
      xs[j * 4 + 0] = xv.x / sv.x;     // IEEE div: matches reference xs
      xs[j * 4 + 1] = xv.y / sv.y;
      xs[j * 4 + 2] = xv.z / sv.z;
      xs[j * 4 + 3] = xv.w / sv.w;
    }
    float m = 0.f;
#pragma unroll
    for (int j = 0; j < 32; ++j) m = fmaxf(m, fabsf(xs[j]));
    m = fmaxf(m, __shfl_xor(m, 1));    // pair covers the 64-col group
    float ascale = m / 7.0f;           // IEEE div: matches reference
    if (ascale == 0.0f) ascale = 1.0f;

    __syncthreads();                   // prev chunk's MFMA readers done
#pragma unroll
    for (int j = 0; j < 4; ++j) {      // 4 chunks of 8 bf16
      short8 w8, s8;
#pragma unroll
      for (int e = 0; e < 8; ++e) {
        float a = xs[j * 8 + e];
        float q = fminf(7.0f, fmaxf(-8.0f, rintf(a / ascale)));  // half-even
        w8[e] = (short)f2bf(q * ascale);
        s8[e] = (short)f2bf(a);
      }
      *(short8*)(arow + c0 + j * 8) = w8;                 // xdq -> A'
      int c = seg * 4 + j;
      int slot = c ^ (row & 7);
      *(short8*)((char*)sxs + (row * 64 + slot) * 16) = s8;  // xs -> LDS
    }
    __syncthreads();
#pragma unroll
    for (int kk = 0; kk < 4; ++kk) {
      int crel = wave * 16 + kk * 4 + quad;    // 8-col chunk index in chunk
      int slot = crel ^ (l16 & 7);
      short8 af = *(const short8*)((const char*)sxs + (l16 * 64 + slot) * 16);
      int kg = cbase + wave * 128 + kk * 32 + quad * 8;
      short8 b0 = *(const short8*)(pdT + (size_t)l16 * IN_DIM + kg);
      short8 b1 = *(const short8*)(pdT + (size_t)(16 + l16) * IN_DIM + kg);
      acc0 = __builtin_amdgcn_mfma_f32_16x16x32_bf16(af, b0, acc0, 0, 0, 0);
      acc1 = __builtin_amdgcn_mfma_f32_16x16x32_bf16(af, b1, acc1, 0, 0, 0);
    }
  }
  // split-K reduce across waves; C layout: col=l16 (rank), row=quad*4+e (token)
#pragma unroll
  for (int e = 0; e < 4; ++e) {
    sacc[wave][quad * 4 + e][l16] = acc0[e];
    sacc[wave][quad * 4 + e][16 + l16] = acc1[e];
  }
  __syncthreads();
  for (int t = tid; t < 512; t += 256) {
    int r2 = t >> 5, rk = t & 31;
    float s = sacc[0][r2][rk] + sacc[1][r2][rk] + sacc[2][r2][rk] + sacc[3][r2][rk];
    lpart[((size_t)slice * T_DIM + (t0 + r2)) * RANK + rk] = s;
  }
}

// ---------------- lora partial reduce -> A' + zero pad ----------------
__global__ __launch_bounds__(256) void k_fixup(const float* __restrict__ lpart,
                                               u16* __restrict__ A) {
  int id = blockIdx.x * 256 + threadIdx.x;   // T*32 = 262144
  int t = id >> 5, c = id & 31;
  size_t base = (size_t)t * RANK + c;
  float s = lpart[base] + lpart[(size_t)T_DIM * RANK + base] +
            lpart[(size_t)2 * T_DIM * RANK + base] +
            lpart[(size_t)3 * T_DIM * RANK + base];
  A[(size_t)t * KP + LORA_OFF + c] = f2bf(s);
  A[(size_t)t * KP + ZPAD_OFF + c] = 0;
}

// ---------------- main GEMM: out = A'[T][KP] @ B'[OUT][KP]^T ----------------
// R4-exact. 256x256 tile, BK=64, 512 threads (8 waves, 2M x 4N), 128 KiB LDS.
// XOR swizzle: row r, 16B-chunk slot c holds global chunk c^(r&7) (staged via
// pre-swizzled global source + linear LDS dest; read with the same XOR).
// Per K-tile window, 4 phases (m0n0, m0n1, m1n0, m1n1), 16 MFMA each;
// stages run 3 half-tiles ahead on 2 buffers; vmcnt(6) once per window.
#define MFMA __builtin_amdgcn_mfma_f32_16x16x32_bf16
#define BAR __builtin_amdgcn_s_barrier

#define STAGE(gbase, sbase, h, ts)                                            \
  do {                                                                        \
    const u16* _s = (gbase) + (size_t)((h)*128 + stg_r) * KP + (ts)*64 + stg_sc * 8; \
    u16* _d = (sbase) + ((h)*128 + stg_r) * 64 + stg_c * 8;                   \
    __builtin_amdgcn_global_load_lds((gas_u32*)(const void*)_s,               \
                                     (las_u32*)(void*)_d, 16, 0, 0);          \
    __builtin_amdgcn_global_load_lds((gas_u32*)(const void*)(_s + (size_t)8 * KP), \
                                     (las_u32*)(void*)(_d + 8 * 64), 16, 0, 0); \
  } while (0)

#define LDA(base, i, kq) \
  (*(const short8*)((base) + ((i)*32 + wr16 + l16) * 64 + (((kq) ^ l7)) * 8))
#define LDB(base, j, kq) \
  (*(const short8*)((base) + ((j)*64 + wc16 + l16) * 64 + (((kq) ^ l7)) * 8))

__global__ __launch_bounds__(512, 2) void k_gemm(const u16* __restrict__ A,
                                                 const u16* __restrict__ B,
                                                 float* __restrict__ C) {
  extern __shared__ __align__(16) u16 lds[];   // 131072 B
  const int tid = threadIdx.x;
  const int wave = tid >> 6, lane = tid & 63;
  const int quad = lane >> 4, l16 = lane & 15, l7 = lane & 7;
  const int wr16 = (wave >> 2) << 4;           // M-wave offset within 32-row group
  const int wc16 = (wave & 3) << 4;            // N-wave offset within 64-row group
  // XCD-aware bijective swizzle (nwg=512, 512%8==0)
  const int swz = (blockIdx.x & 7) * 64 + (blockIdx.x >> 3);
  const int t0 = (swz >> 4) * 256;             // 32 M-tiles
  const int o0 = (swz & 15) * 256;             // 16 N-tiles
  const u16* gA = A + (size_t)t0 * KP;
  const u16* gB = B + (size_t)o0 * KP;
  // staging constants: row within 128-row half, LDS chunk slot, source chunk
  const int stg_r = wave * 16 + (lane >> 3);
  const int stg_c = lane & 7;
  const int stg_sc = stg_c ^ (lane >> 3);

  u16* const sA0 = lds;
  u16* const sB0 = lds + 16384;
  u16* const sA1 = lds + 32768;
  u16* const sB1 = lds + 32768 + 16384;

  f32x4 acc[8][4];
#pragma unroll
  for (int i = 0; i < 8; ++i)
#pragma unroll
    for (int j = 0; j < 4; ++j)
      acc[i][j] = (f32x4){0.f, 0.f, 0.f, 0.f};

  // Prologue: tile0 complete + 3 halves of tile1; leaves the steady-state
  // in-flight set {Am0(1), Bn0(1), Bn1(1)} == 3 halves == vmcnt(6).
  STAGE(gA, sA0, 0, 0);
  STAGE(gB, sB0, 0, 0);
  STAGE(gB, sB0, 1, 0);
  STAGE(gA, sA0, 1, 0);
  STAGE(gA, sA1, 0, 1);
  STAGE(gB, sB1, 0, 1);
  STAGE(gB, sB1, 1, 1);
  asm volatile("s_waitcnt vmcnt(6)" ::: "memory");
  BAR();

  for (int t = 0; t < NT; ++t) {
    const int cur = t & 1;
    int ts1 = t + 1; if (ts1 >= NT) ts1 = NT - 1;   // clamped phantom stages
    int ts2 = t + 2; if (ts2 >= NT) ts2 = NT - 1;   // keep vmcnt counts uniform
    u16* const sAc = cur ? sA1 : sA0;
    u16* const sBc = cur ? sB1 : sB0;
    u16* const sAn = cur ? sA0 : sA1;

    short8 a[4][2], b0[2][2], b1[2][2];

    // ---- P1: m0 x n0 (reads Am0(t), Bn0(t)) ----
#pragma unroll
    for (int i = 0; i < 4; ++i) {
      a[i][0] = LDA(sAc, i, quad);
      a[i][1] = LDA(sAc, i, 4 + quad);
    }
#pragma unroll
    for (int j = 0; j < 2; ++j) {
      b0[j][0] = LDB(sBc, j, quad);
      b0[j][1] = LDB(sBc, j, 4 + quad);
    }
    STAGE(gA, sAn, 1, ts1);            // Am1(t+1); region freed at t-1's P3
    BAR();
    __builtin_amdgcn_s_setprio(1);
#pragma unroll
    for (int i = 0; i < 4; ++i)
#pragma unroll
      for (int j = 0; j < 2; ++j) {
        acc[i][j] = MFMA(a[i][0], b0[j][0], acc[i][j], 0, 0, 0);
        acc[i][j] = MFMA(a[i][1], b0[j][1], acc[i][j], 0, 0, 0);
      }
    __builtin_amdgcn_s_setprio(0);
    BAR();

    // ---- P2: m0 x n1 (reads Bn1(t); A m0 reused from regs) ----
#pragma unroll
    for (int j = 0; j < 2; ++j) {
      b1[j][0] = LDB(sBc, 2 + j, quad);
      b1[j][1] = LDB(sBc, 2 + j, 4 + quad);
    }
    STAGE(gA, sAc, 0, ts2);            // Am0(t+2); region freed by P1 reads
    BAR();
    __builtin_amdgcn_s_setprio(1);
#pragma unroll
    for (int i = 0; i < 4; ++i)
#pragma unroll
      for (int j = 0; j < 2; ++j) {
        acc[i][2 + j] = MFMA(a[i][0], b1[j][0], acc[i][2 + j], 0, 0, 0);
        acc[i][2 + j] = MFMA(a[i][1], b1[j][1], acc[i][2 + j], 0, 0, 0);
      }
    __builtin_amdgcn_s_setprio(0);
    BAR();

    // ---- P3: m1 x n0 (reads Am1(t); B n0 reused from regs) ----
#pragma unroll
    for (int i = 0; i < 4; ++i) {
      a[i][0] = LDA(sAc, 4 + i, quad);
      a[i][1] = LDA(sAc, 4 + i, 4 + quad);
    }
    STAGE(gB, sBc, 0, ts2);            // Bn0(t+2); region freed by P1 reads
    BAR();
    __builtin_amdgcn_s_setprio(1);
#pragma unroll
    for (int i = 0; i < 4; ++i)
#pragma unroll
      for (int j = 0; j < 2; ++j) {
        acc[4 + i][j] = MFMA(a[i][0], b0[j][0], acc[4 + i][j], 0, 0, 0);
        acc[4 + i][j] = MFMA(a[i][1], b0[j][1], acc[4 + i][j], 0, 0, 0);
      }
    __builtin_amdgcn_s_setprio(0);
    BAR();

    // ---- P4: m1 x n1 (no LDS reads) ----
    STAGE(gB, sBc, 1, ts2);            // Bn1(t+2); region freed by P2 reads
    BAR();
    __builtin_amdgcn_s_setprio(1);
#pragma unroll
    for (int i = 0; i < 4; ++i)
#pragma unroll
      for (int j = 0; j < 2; ++j) {
        acc[4 + i][2 + j] = MFMA(a[i][0], b1[j][0], acc[4 + i][2 + j], 0, 0, 0);
        acc[4 + i][2 + j] = MFMA(a[i][1], b1[j][1], acc[4 + i][2 + j], 0, 0, 0);
      }
    __builtin_amdgcn_s_setprio(0);
    // Wait tile t+1 fully landed (= everything except the 3 halves of t+2
    // staged this window). Never drains in-flight prefetch to 0.
    asm volatile("s_waitcnt vmcnt(6)" ::: "memory");
    BAR();
  }

  // Epilogue: acc[i][j] -> C rows t0 + i*32 + wr16 + quad*4 + e,
  //                        cols o0 + j*64 + wc16 + l16
#pragma unroll
  for (int i = 0; i < 8; ++i) {
    const int row = t0 + i * 32 + wr16 + quad * 4;
#pragma unroll
    for (int j = 0; j < 4; ++j) {
      const int col = o0 + j * 64 + wc16 + l16;
#pragma unroll
      for (int e = 0; e < 4; ++e)
        C[(size_t)(row + e) * OUT_DIM + col] = acc[i][j][e];
    }
  }
}

extern "C" void kernel_launch(void* const* d_in, const int* in_sizes, int n_in,
                              void* d_out, int out_size, void* d_ws, size_t ws_size,
                              hipStream_t stream) {
  const float* x      = (const float*)d_in[0];
  const int*   qw     = (const int*)d_in[1];
  const float* wsc    = (const float*)d_in[2];
  const float* smooth = (const float*)d_in[3];
  const float* pd     = (const float*)d_in[4];
  const float* pu     = (const float*)d_in[5];
  float* out = (float*)d_out;

  char* ws = (char*)d_ws;
  u16*   A     = (u16*)ws;                                 // 68,157,440 B
  u16*   B     = (u16*)(ws + 68157440);                    // 34,078,720 B
  u16*   pdT   = (u16*)(ws + 102236160);                   //    262,144 B
  float* lpart = (float*)(ws + 102498304);                 //  4,194,304 B

  static int attr_set = 0;
  if (!attr_set) {
    hipFuncSetAttribute(reinterpret_cast<const void*>(k_gemm),
                        hipFuncAttributeMaxDynamicSharedMemorySize, 131072);
    attr_set = 1;
  }

  k_wdq  <<<dim3(OUT_DIM * 4), dim3(256), 0, stream>>>(qw, wsc, B);
  k_wlora<<<dim3(OUT_DIM * 64 / 256), dim3(256), 0, stream>>>(pu, B);
  k_prep <<<dim3(IN_DIM * RANK / 256), dim3(256), 0, stream>>>(pd, pdT);
  k_act  <<<dim3(2048), dim3(256), 0, stream>>>(x, smooth, pdT, A, lpart);
  k_fixup<<<dim3(T_DIM * RANK / 256), dim3(256), 0, stream>>>(lpart, A);
  k_gemm <<<dim3(512), dim3(512), 131072, stream>>>(A, B, out);
}